// Round 14
// baseline (191.554 us; speedup 1.0000x reference)
//
#include <hip/hip_runtime.h>
#include <hip/hip_bf16.h>

// Bahdanau attention (R14) = R13 pipeline + 8-phase 256^2 score GEMM (m201 template):
//   T3 8-phase split, T4 counted vmcnt(4), T2 XOR slot swizzle (pre-swizzled global
//   source, linear gload_lds dest), T5 setprio around MFMA clusters.
//   BM=BN=256, BK=64, 512thr/8 waves (2Mx4N), wave tile 128x64, acc[8][4], LDS 128KB.
//   Mask compaction: score/softmax/ctx run only on ~50% unmasked rows (pad to 256).

#define NB 32
#define SS 2048
#define HD 1024
#define HE 1024
#define MM (NB * SS)
#define NKT 16         // K-tiles of 64 (K=1024)

typedef float f32x4 __attribute__((ext_vector_type(4)));
typedef short bf16x8 __attribute__((ext_vector_type(8)));
typedef short short4v __attribute__((ext_vector_type(4)));

static __device__ __forceinline__ short f2bf(float f) {
    union { __hip_bfloat16 h; short s; } u;
    u.h = __float2bfloat16(f);
    return u.s;
}
static __device__ __forceinline__ float bf2f(short s) {
    union { float f; unsigned u; } u;
    u.u = ((unsigned)(unsigned short)s) << 16;
    return u.f;
}

static __device__ __forceinline__ void gload16(const void* g, const void* l) {
    __builtin_amdgcn_global_load_lds(
        (const __attribute__((address_space(1))) void*)(uintptr_t)(g),
        (__attribute__((address_space(3))) void*)(unsigned)(uintptr_t)(l),
        16, 0, 0);
}

// ---------------- per-batch mask compaction ----------------
__global__ __launch_bounds__(64) void compact_kernel(const int* __restrict__ mask,
                                                     int* __restrict__ idx,
                                                     int* __restrict__ cnt) {
    const int b = blockIdx.x;
    const int lane = threadIdx.x;
    int base = 0;
    for (int s0 = 0; s0 < SS; s0 += 64) {
        const int m = mask[b * SS + s0 + lane];
        const unsigned long long bal = __ballot(m != 0);
        const int rank = __popcll(bal & ((1ull << lane) - 1ull));
        if (m) idx[b * SS + base + rank] = s0 + lane;
        base += (int)__popcll(bal);
    }
    if (lane == 0) cnt[b] = base;
    for (int j = base + lane; j < SS; j += 64) idx[b * SS + j] = 0;
}

// ---------------- f32 -> bf16 (Wk) ----------------
__global__ __launch_bounds__(256) void cvt_bf16_kernel(const float* __restrict__ in,
                                                       short* __restrict__ out, int n8) {
    int i = blockIdx.x * 256 + threadIdx.x;
    const int stride = gridDim.x * 256;
    for (; i < n8; i += stride) {
        const f32x4 a = *(const f32x4*)(in + (long)i * 8);
        const f32x4 b = *(const f32x4*)(in + (long)i * 8 + 4);
        bf16x8 o;
        o[0] = f2bf(a[0]); o[1] = f2bf(a[1]); o[2] = f2bf(a[2]); o[3] = f2bf(a[3]);
        o[4] = f2bf(b[0]); o[5] = f2bf(b[1]); o[6] = f2bf(b[2]); o[7] = f2bf(b[3]);
        *(bf16x8*)(out + (long)i * 8) = o;
    }
}

// ---------------- gather + cvt enc rows -> compacted bf16, zero-pad to 256 ----------------
__global__ __launch_bounds__(256) void cvt_enc_kernel(const float* __restrict__ enc,
                                                      const int* __restrict__ idx,
                                                      const int* __restrict__ cnt,
                                                      short* __restrict__ encb) {
    const int b  = blockIdx.x >> 7;
    const int j0 = (blockIdx.x & 127) * 16;
    const int n  = cnt[b];
    const int nr = (n + 255) & ~255;       // pad to 256 for BM=256 tiles
    if (j0 >= nr) return;
    const int j  = j0 + (threadIdx.x >> 4);
    const int c0 = (threadIdx.x & 15) * 8;
    short* dst = encb + ((long)b * SS + j) * HE + c0;
    if (j < n) {
        const float* src = enc + ((long)b * SS + idx[b * SS + j]) * HE + c0;
        #pragma unroll
        for (int u = 0; u < 8; ++u) {
            const f32x4 x = *(const f32x4*)(src + u * 128);
            const f32x4 y = *(const f32x4*)(src + u * 128 + 4);
            bf16x8 o;
            o[0] = f2bf(x[0]); o[1] = f2bf(x[1]); o[2] = f2bf(x[2]); o[3] = f2bf(x[3]);
            o[4] = f2bf(y[0]); o[5] = f2bf(y[1]); o[6] = f2bf(y[2]); o[7] = f2bf(y[3]);
            *(bf16x8*)(dst + u * 128) = o;
        }
    } else {
        const bf16x8 z = (bf16x8){0,0,0,0,0,0,0,0};
        #pragma unroll
        for (int u = 0; u < 8; ++u) *(bf16x8*)(dst + u * 128) = z;
    }
}

// ---------------- q = dh @ Wq^T ----------------
__global__ __launch_bounds__(256) void qproj_kernel(const float* __restrict__ dh,
                                                    const float* __restrict__ Wq,
                                                    float* __restrict__ q) {
    const int wid  = threadIdx.x >> 6;
    const int lane = threadIdx.x & 63;
    const int d    = blockIdx.x * 4 + wid;
    const float* wrow = Wq + (long)d * HD + lane * 16;
    f32x4 w0 = *(const f32x4*)(wrow + 0);
    f32x4 w1 = *(const f32x4*)(wrow + 4);
    f32x4 w2 = *(const f32x4*)(wrow + 8);
    f32x4 w3 = *(const f32x4*)(wrow + 12);
    for (int b = 0; b < NB; ++b) {
        const float* drow = dh + b * HD + lane * 16;
        f32x4 d0 = *(const f32x4*)(drow + 0);
        f32x4 d1 = *(const f32x4*)(drow + 4);
        f32x4 d2 = *(const f32x4*)(drow + 8);
        f32x4 d3 = *(const f32x4*)(drow + 12);
        f32x4 s4 = w0 * d0 + w1 * d1 + w2 * d2 + w3 * d3;
        float dot = s4[0] + s4[1] + s4[2] + s4[3];
        #pragma unroll
        for (int off = 32; off > 0; off >>= 1)
            dot += __shfl_xor(dot, off, 64);
        if (lane == 0) q[b * HD + d] = dot;
    }
}

// ---------------- 8-phase 256x256 score GEMM over compacted rows ----------------
// LDS map (bytes): A = [0,65536): buf*32768 + half*16384 + row*128 + slot*16
//                  B = [65536,131072): same.  slot swizzle: phys = logical ^ (row&7).
__global__ __launch_bounds__(512, 2) void score_8ph_kernel(const short* __restrict__ encb,
                                                           const short* __restrict__ wkb,
                                                           const float* __restrict__ qv,
                                                           const float* __restrict__ ven,
                                                           const int* __restrict__ cnt,
                                                           float* __restrict__ sp) {
    __shared__ __align__(16) char Ls[131072];

    // XCD swizzle: 4 consecutive slots (one mtile's N-tiles) per XCD
    const int bid   = blockIdx.x;
    const int xcd   = bid & 7;
    const int slot  = bid >> 3;                 // 0..127
    const int mtile = xcd * 32 + (slot >> 2);   // 0..255
    const int nt    = slot & 3;
    const int bb    = mtile >> 3;               // batch
    const int tile  = mtile & 7;                // 256-row tile in batch
    if (tile * 256 >= cnt[bb]) return;

    const int tid  = threadIdx.x;
    const int lane = tid & 63;
    const int wid  = tid >> 6;                  // 0..7
    const int wr   = wid >> 2;                  // 0..1  (M half: 128 rows)
    const int wc   = wid & 3;                   // 0..3  (N quarter: 64 cols)
    const long mbase = (long)bb * SS + tile * 256;
    const int  nbase = nt * 256;

    f32x4 acc[8][4] = {};
    bf16x8 bfr[2][4];

    // staging: half-tile = 128 rows x 64 cols = 1024 x 16B chunks; thread covers
    // chunks tid (j=0) and tid+512 (j=1): row = chunk>>3, slot = tid&7.
    // global source pre-swizzled: fetch logical slot (tid&7)^(row&7).
    const int srow  = tid >> 3;                 // 0..63
    const int swoff = ((tid & 7) ^ (srow & 7)) * 8;   // shorts
    const short* aG = encb + (mbase + srow) * (long)HE + swoff;
    const short* bG = wkb + ((long)(nbase + srow)) * HE + swoff;

    #define STG(OPG, OPBASE, BUF, HALF, KT)                                          \
        do {                                                                         \
            gload16(OPG + (KT) * 64 + (HALF) * 128 * (long)HE,                       \
                    Ls + (OPBASE) + (BUF) * 32768 + (HALF) * 16384 + (wid * 64) * 16); \
            gload16(OPG + (KT) * 64 + (HALF) * 128 * (long)HE + 64 * (long)HE,       \
                    Ls + (OPBASE) + (BUF) * 32768 + (HALF) * 16384 + 8192 + (wid * 64) * 16); \
        } while (0)

    // read-side constants: phys slot = ((lane>>4) + ks*4) ^ (frow&7)
    const int frow = lane & 15;
    const int kb0  = (((lane >> 4) ^ (frow & 7)) * 16);
    const int kb1  = kb0 ^ 64;
    const char* aRd = Ls + wr * 16384 + frow * 128;   // + buf*32768 + m*2048 + kb
    int bOff[4];
    #pragma unroll
    for (int n = 0; n < 4; ++n) {
        const int RB = wc * 64 + n * 16 + frow;       // B row 0..255
        bOff[n] = 65536 + (RB >> 7) * 16384 + (RB & 127) * 128;
    }

    // phase: [ds_reads][stage 1 half-tile][barrier][lgkm0][16 MFMA][close barrier]
    #define PH(BUF, Q, FIRST, STAGE_CODE, CLOSE_CODE)                                \
        do {                                                                         \
            if (FIRST) {                                                             \
                _Pragma("unroll")                                                    \
                for (int n = 0; n < 4; ++n) {                                        \
                    bfr[0][n] = *(const bf16x8*)(Ls + bOff[n] + (BUF) * 32768 + kb0);\
                    bfr[1][n] = *(const bf16x8*)(Ls + bOff[n] + (BUF) * 32768 + kb1);\
                }                                                                    \
            }                                                                        \
            bf16x8 a0k0 = *(const bf16x8*)(aRd + (BUF) * 32768 + (2 * (Q)) * 2048 + kb0);     \
            bf16x8 a0k1 = *(const bf16x8*)(aRd + (BUF) * 32768 + (2 * (Q)) * 2048 + kb1);     \
            bf16x8 a1k0 = *(const bf16x8*)(aRd + (BUF) * 32768 + (2 * (Q) + 1) * 2048 + kb0); \
            bf16x8 a1k1 = *(const bf16x8*)(aRd + (BUF) * 32768 + (2 * (Q) + 1) * 2048 + kb1); \
            STAGE_CODE;                                                              \
            asm volatile("s_barrier" ::: "memory");                                  \
            asm volatile("s_waitcnt lgkmcnt(0)" ::: "memory");                       \
            __builtin_amdgcn_sched_barrier(0);                                       \
            __builtin_amdgcn_s_setprio(1);                                           \
            _Pragma("unroll")                                                        \
            for (int n = 0; n < 4; ++n) {                                            \
                acc[2*(Q)][n]   = __builtin_amdgcn_mfma_f32_16x16x32_bf16(a0k0, bfr[0][n], acc[2*(Q)][n], 0, 0, 0);   \
                acc[2*(Q)+1][n] = __builtin_amdgcn_mfma_f32_16x16x32_bf16(a1k0, bfr[0][n], acc[2*(Q)+1][n], 0, 0, 0); \
                acc[2*(Q)][n]   = __builtin_amdgcn_mfma_f32_16x16x32_bf16(a0k1, bfr[1][n], acc[2*(Q)][n], 0, 0, 0);   \
                acc[2*(Q)+1][n] = __builtin_amdgcn_mfma_f32_16x16x32_bf16(a1k1, bfr[1][n], acc[2*(Q)+1][n], 0, 0, 0); \
            }                                                                        \
            __builtin_amdgcn_s_setprio(0);                                           \
            __builtin_amdgcn_sched_barrier(0);                                       \
            CLOSE_CODE;                                                              \
        } while (0)

    // ---- prologue: stage tile0 fully (8 loads) + tile1 B halves (4 loads) ----
    STG(bG, 65536, 0, 0, 0);  STG(bG, 65536, 0, 1, 0);
    STG(aG, 0,     0, 0, 0);  STG(aG, 0,     0, 1, 0);
    STG(bG, 65536, 1, 0, 1);  STG(bG, 65536, 1, 1, 1);
    asm volatile("s_waitcnt vmcnt(4)\ns_barrier" ::: "memory");   // tile0 landed

    // ---- main loop: iter t consumes tiles 2t (buf0) then 2t+1 (buf1) ----
    for (int t = 0; t < 8; ++t) {
        const int k0 = 2 * t;
        // phases 0-3: tile 2t, buf0, quadrants 0..3
        PH(0, 0, true,  { STG(aG, 0, 1, 0, k0 + 1); },
           asm volatile("s_barrier" ::: "memory"));
        PH(0, 1, false, { STG(aG, 0, 1, 1, k0 + 1); },
           asm volatile("s_barrier" ::: "memory"));
        PH(0, 2, false, { if (t < 7) STG(bG, 65536, 0, 0, k0 + 2); },
           asm volatile("s_barrier" ::: "memory"));
        PH(0, 3, false, { if (t < 7) STG(bG, 65536, 0, 1, k0 + 2); },
           { if (t < 7) asm volatile("s_waitcnt vmcnt(4)\ns_barrier" ::: "memory");
             else       asm volatile("s_waitcnt vmcnt(0)\ns_barrier" ::: "memory"); });
        // phases 4-7: tile 2t+1, buf1, quadrants 0..3
        PH(1, 0, true,  { if (t < 7) STG(aG, 0, 0, 0, k0 + 2); },
           asm volatile("s_barrier" ::: "memory"));
        PH(1, 1, false, { if (t < 7) STG(aG, 0, 0, 1, k0 + 2); },
           asm volatile("s_barrier" ::: "memory"));
        PH(1, 2, false, { if (t < 7) STG(bG, 65536, 1, 0, k0 + 3); },
           asm volatile("s_barrier" ::: "memory"));
        PH(1, 3, false, { if (t < 7) STG(bG, 65536, 1, 1, k0 + 3); },
           { if (t < 7) asm volatile("s_waitcnt vmcnt(4)\ns_barrier" ::: "memory");
             else       asm volatile("s_barrier" ::: "memory"); });
    }
    #undef PH
    #undef STG

    // ---- epilogue: partial score over this wave's 64 cols ----
    // C/D: col = lane&15, row = (lane>>4)*4 + reg
    float qq[4], vv[4];
    #pragma unroll
    for (int n = 0; n < 4; ++n) {
        const int c = nbase + wc * 64 + n * 16 + frow;
        qq[n] = qv[bb * HD + c];
        vv[n] = ven[c];
    }
    float p[8][4];
    #pragma unroll
    for (int m = 0; m < 8; ++m) {
        #pragma unroll
        for (int rg = 0; rg < 4; ++rg) {
            float s = 0.f;
            #pragma unroll
            for (int n = 0; n < 4; ++n) {
                const float x = acc[m][n][rg] + qq[n];
                const float e = __expf(2.f * x);
                const float t = 1.f - 2.f * __builtin_amdgcn_rcpf(e + 1.f);
                s += vv[n] * t;
            }
            #pragma unroll
            for (int msk = 1; msk <= 8; msk <<= 1)
                s += __shfl_xor(s, msk, 64);
            p[m][rg] = s;
        }
    }
    if ((lane & 15) == 0) {
        const int g = lane >> 4;
        float* dst = sp + (long)(nt * 4 + wc) * MM;   // 16 deterministic slots
        #pragma unroll
        for (int m = 0; m < 8; ++m)
            #pragma unroll
            for (int rg = 0; rg < 4; ++rg)
                dst[mbase + wr * 128 + m * 16 + g * 4 + rg] = p[m][rg];
    }
}

// ---------------- softmax over compacted domain; zero + scatter to attn ----------------
__global__ __launch_bounds__(256) void softmax_kernel(const float* __restrict__ sp,
                                                      const int* __restrict__ idx,
                                                      const int* __restrict__ cnt,
                                                      float* __restrict__ attn,
                                                      float* __restrict__ wcomp) {
    const int b = blockIdx.x;
    const int tid = threadIdx.x;
    const int lane = tid & 63;
    const int wid = tid >> 6;
    const int n = cnt[b];
    #pragma unroll
    for (int i = 0; i < 8; ++i)
        attn[b * SS + tid + i * 256] = 0.f;
    __shared__ float red[4];
    float sc[8];
    float mx = -3.0e38f;
    #pragma unroll
    for (int i = 0; i < 8; ++i) {
        const int j = tid + i * 256;
        float v = -3.0e38f;
        if (j < n) {
            v = 0.f;
            #pragma unroll
            for (int k = 0; k < 16; ++k)
                v += sp[(long)k * MM + b * SS + j];
        }
        sc[i] = v;
        mx = fmaxf(mx, v);
    }
    #pragma unroll
    for (int off = 32; off > 0; off >>= 1)
        mx = fmaxf(mx, __shfl_xor(mx, off, 64));
    if (lane == 0) red[wid] = mx;
    __syncthreads();
    mx = fmaxf(fmaxf(red[0], red[1]), fmaxf(red[2], red[3]));
    __syncthreads();
    float sum = 0.f;
    #pragma unroll
    for (int i = 0; i < 8; ++i) {
        const float e = (sc[i] > -1.0e38f) ? __expf(sc[i] - mx) : 0.f;
        sc[i] = e;
        sum += e;
    }
    #pragma unroll
    for (int off = 32; off > 0; off >>= 1)
        sum += __shfl_xor(sum, off, 64);
    if (lane == 0) red[wid] = sum;
    __syncthreads();
    sum = red[0] + red[1] + red[2] + red[3];
    const float inv = 1.f / sum;
    #pragma unroll
    for (int i = 0; i < 8; ++i) {
        const int j = tid + i * 256;
        const float w = sc[i] * inv;
        wcomp[b * SS + j] = w;
        if (j < n) attn[b * SS + idx[b * SS + j]] = w;
    }
}

// ---------------- context over compacted bf16 rows ----------------
__global__ __launch_bounds__(256) void ctx_partial_kernel(const short* __restrict__ encb,
                                                          const float* __restrict__ wcomp,
                                                          const int* __restrict__ cnt,
                                                          float* __restrict__ cp) {
    const int b = blockIdx.x >> 5;
    const int chunk = blockIdx.x & 31;
    const int tid = threadIdx.x;
    float* dst = cp + ((long)(b * 32 + chunk)) * HE + tid * 4;
    if (chunk * 64 >= cnt[b]) {
        *(f32x4*)dst = (f32x4){0.f, 0.f, 0.f, 0.f};
        return;
    }
    const short* ep = encb + ((long)b * SS + chunk * 64) * HE + tid * 4;
    const float* ap = wcomp + b * SS + chunk * 64;
    f32x4 acc = (f32x4){0.f, 0.f, 0.f, 0.f};
    #pragma unroll 4
    for (int s = 0; s < 64; ++s) {
        const float w = ap[s];
        const short4v v = *(const short4v*)(ep + (long)s * HE);
        acc[0] += w * bf2f(v[0]);
        acc[1] += w * bf2f(v[1]);
        acc[2] += w * bf2f(v[2]);
        acc[3] += w * bf2f(v[3]);
    }
    *(f32x4*)dst = acc;
}

__global__ __launch_bounds__(256) void ctx_reduce_kernel(const float* __restrict__ cp,
                                                         float* __restrict__ out) {
    const int o = blockIdx.x * 256 + threadIdx.x;
    const int b = o >> 10;
    const int e = o & 1023;
    float s = 0.f;
    #pragma unroll
    for (int c = 0; c < 32; ++c)
        s += cp[((long)(b * 32 + c)) * HE + e];
    out[o] = s;
}

extern "C" void kernel_launch(void* const* d_in, const int* in_sizes, int n_in,
                              void* d_out, int out_size, void* d_ws, size_t ws_size,
                              hipStream_t stream) {
    const float* dh   = (const float*)d_in[0];
    const float* enc  = (const float*)d_in[1];
    const int*   mask = (const int*)d_in[2];
    const float* Wq   = (const float*)d_in[3];
    const float* Wk   = (const float*)d_in[4];
    const float* Ve   = (const float*)d_in[5];

    float* out  = (float*)d_out;
    float* ctx  = out;
    float* attn = out + NB * HD;

    float* ws    = (float*)d_ws;
    float* wq_   = ws;                            // 32768 f
    float* sp    = ws + 32768;                    // 16 * 65536 f (4 MB)
    float* cp    = sp + 16 * (long)MM;            // 32*32*1024 f (4 MB)
    short* wkb   = (short*)(cp + 32 * 32 * HE);   // 1M bf16 (2 MB)
    float* wcomp = (float*)(wkb + (long)HD * HE); // 65536 f
    int*   idx   = (int*)(wcomp + MM);            // 65536 i
    int*   cnt   = idx + MM;                      // 32 i (+pad)
    short* encb  = (short*)(cnt + 64);            // 67.1M bf16 (128 MB)

    compact_kernel<<<NB, 64, 0, stream>>>(mask, idx, cnt);
    qproj_kernel<<<256, 256, 0, stream>>>(dh, Wq, wq_);
    cvt_bf16_kernel<<<512, 256, 0, stream>>>(Wk, wkb, HD * HE / 8);
    cvt_enc_kernel<<<NB * 128, 256, 0, stream>>>(enc, idx, cnt, encb);
    score_8ph_kernel<<<1024, 512, 0, stream>>>(encb, wkb, wq_, Ve, cnt, sp);
    softmax_kernel<<<NB, 256, 0, stream>>>(sp, idx, cnt, attn, wcomp);
    ctx_partial_kernel<<<1024, 256, 0, stream>>>(encb, wcomp, cnt, cp);
    ctx_reduce_kernel<<<128, 256, 0, stream>>>(cp, ctx);
}

// Round 15
// 164.195 us; speedup vs baseline: 1.1666x; 1.1666x over previous
//
#include <hip/hip_runtime.h>
#include <hip/hip_bf16.h>

// Bahdanau attention (R15) = R13 (best: 181.8us) with front kernels fused:
//   prep_kernel = compact (blocks 0-7, 4 batches ea) | qproj (8-263) | cvt_wk (264-775)
//   cvt_enc: gather unmasked rows -> compacted bf16 encb (zero-pad to 128)
//   score:   m97-style 128x128 bf16 GEMM over compacted rows, 4 waves, acc[4][4],
//            A+B via global_load_lds, 2 K-tiles per sync epoch, 3 blocks/CU,
//            XCD swizzle, fused tanh/v-dot epilogue       (unchanged from R13)
//   softmax over compacted domain (zeroes attn, scatters weights)
//   ctx over compacted bf16 rows.

#define NB 32
#define SS 2048
#define HD 1024
#define HE 1024
#define MM (NB * SS)   // compacted (padded) row space
#define NT 32          // K-tiles = HE/32

typedef float f32x4 __attribute__((ext_vector_type(4)));
typedef short bf16x8 __attribute__((ext_vector_type(8)));
typedef short short4v __attribute__((ext_vector_type(4)));

static __device__ __forceinline__ short f2bf(float f) {
    union { __hip_bfloat16 h; short s; } u;
    u.h = __float2bfloat16(f);
    return u.s;
}
static __device__ __forceinline__ float bf2f(short s) {
    union { float f; unsigned u; } u;
    u.u = ((unsigned)(unsigned short)s) << 16;
    return u.f;
}

static __device__ __forceinline__ void gload16(const void* g, const void* l) {
    __builtin_amdgcn_global_load_lds(
        (const __attribute__((address_space(1))) void*)(uintptr_t)(g),
        (__attribute__((address_space(3))) void*)(unsigned)(uintptr_t)(l),
        16, 0, 0);
}

// ---------------- fused prep: compact | qproj | cvt_wk ----------------
// blocks 0-7:    mask compaction, wave w handles batch bid*4 + w
// blocks 8-263:  qproj, one wave per output column d
// blocks 264-775: Wk f32->bf16 (512 blocks x 256 thr x 8 elems = 1M)
__global__ __launch_bounds__(256) void prep_kernel(const int* __restrict__ mask,
                                                   const float* __restrict__ dh,
                                                   const float* __restrict__ Wq,
                                                   const float* __restrict__ Wk,
                                                   int* __restrict__ idx,
                                                   int* __restrict__ cnt,
                                                   float* __restrict__ q,
                                                   short* __restrict__ wkb) {
    const int bid  = blockIdx.x;
    const int tid  = threadIdx.x;
    const int wid  = tid >> 6;
    const int lane = tid & 63;

    if (bid < 8) {
        // ---- compact: this wave owns batch b ----
        const int b = bid * 4 + wid;
        int base = 0;
        for (int s0 = 0; s0 < SS; s0 += 64) {
            const int m = mask[b * SS + s0 + lane];
            const unsigned long long bal = __ballot(m != 0);
            const int rank = __popcll(bal & ((1ull << lane) - 1ull));
            if (m) idx[b * SS + base + rank] = s0 + lane;
            base += (int)__popcll(bal);
        }
        if (lane == 0) cnt[b] = base;
        for (int j = base + lane; j < SS; j += 64) idx[b * SS + j] = 0;
    } else if (bid < 264) {
        // ---- qproj: one wave per column d ----
        const int d = (bid - 8) * 4 + wid;
        const float* wrow = Wq + (long)d * HD + lane * 16;
        f32x4 w0 = *(const f32x4*)(wrow + 0);
        f32x4 w1 = *(const f32x4*)(wrow + 4);
        f32x4 w2 = *(const f32x4*)(wrow + 8);
        f32x4 w3 = *(const f32x4*)(wrow + 12);
        for (int b = 0; b < NB; ++b) {
            const float* drow = dh + b * HD + lane * 16;
            f32x4 d0 = *(const f32x4*)(drow + 0);
            f32x4 d1 = *(const f32x4*)(drow + 4);
            f32x4 d2 = *(const f32x4*)(drow + 8);
            f32x4 d3 = *(const f32x4*)(drow + 12);
            f32x4 s4 = w0 * d0 + w1 * d1 + w2 * d2 + w3 * d3;
            float dot = s4[0] + s4[1] + s4[2] + s4[3];
            #pragma unroll
            for (int off = 32; off > 0; off >>= 1)
                dot += __shfl_xor(dot, off, 64);
            if (lane == 0) q[b * HD + d] = dot;
        }
    } else {
        // ---- cvt_wk: i in [0, 131072) ----
        const int i = (bid - 264) * 256 + tid;
        const f32x4 a = *(const f32x4*)(Wk + (long)i * 8);
        const f32x4 b = *(const f32x4*)(Wk + (long)i * 8 + 4);
        bf16x8 o;
        o[0] = f2bf(a[0]); o[1] = f2bf(a[1]); o[2] = f2bf(a[2]); o[3] = f2bf(a[3]);
        o[4] = f2bf(b[0]); o[5] = f2bf(b[1]); o[6] = f2bf(b[2]); o[7] = f2bf(b[3]);
        *(bf16x8*)(wkb + (long)i * 8) = o;
    }
}

// ---------------- gather + cvt enc rows -> compacted bf16, zero-pad to 128 ----------------
__global__ __launch_bounds__(256) void cvt_enc_kernel(const float* __restrict__ enc,
                                                      const int* __restrict__ idx,
                                                      const int* __restrict__ cnt,
                                                      short* __restrict__ encb) {
    const int b  = blockIdx.x >> 7;
    const int j0 = (blockIdx.x & 127) * 16;
    const int n  = cnt[b];
    const int nr = (n + 127) & ~127;
    if (j0 >= nr) return;
    const int j  = j0 + (threadIdx.x >> 4);
    const int c0 = (threadIdx.x & 15) * 8;
    short* dst = encb + ((long)b * SS + j) * HE + c0;
    if (j < n) {
        const float* src = enc + ((long)b * SS + idx[b * SS + j]) * HE + c0;
        #pragma unroll
        for (int u = 0; u < 8; ++u) {
            const f32x4 x = *(const f32x4*)(src + u * 128);
            const f32x4 y = *(const f32x4*)(src + u * 128 + 4);
            bf16x8 o;
            o[0] = f2bf(x[0]); o[1] = f2bf(x[1]); o[2] = f2bf(x[2]); o[3] = f2bf(x[3]);
            o[4] = f2bf(y[0]); o[5] = f2bf(y[1]); o[6] = f2bf(y[2]); o[7] = f2bf(y[3]);
            *(bf16x8*)(dst + u * 128) = o;
        }
    } else {
        const bf16x8 z = (bf16x8){0,0,0,0,0,0,0,0};
        #pragma unroll
        for (int u = 0; u < 8; ++u) *(bf16x8*)(dst + u * 128) = z;
    }
}

// ---------------- score GEMM: 128x128 tile, 4 waves, 2 K-tiles per epoch (R13) ----------------
__global__ __launch_bounds__(256, 3) void score_mfma_kernel(const short* __restrict__ encb,
                                                            const short* __restrict__ wkb,
                                                            const float* __restrict__ qv,
                                                            const float* __restrict__ ven,
                                                            const int* __restrict__ cnt,
                                                            float* __restrict__ sp) {
    __shared__ __align__(16) short As[2][4096];   // two 8 KB A K-subtiles
    __shared__ __align__(16) short Bs[2][4096];

    // XCD swizzle: 8 sibling N-tiles of an M-tile on one XCD (A L2 reuse)
    const int bid   = blockIdx.x;
    const int xcd   = bid & 7;
    const int slot  = bid >> 3;                 // 0..511
    const int mtile = xcd * 64 + (slot >> 3);   // 0..511
    const int nt    = slot & 7;                 // 0..7

    const int bb   = mtile >> 4;
    const int tile = mtile & 15;
    if (tile * 128 >= cnt[bb]) return;          // masked tail tile: dead

    const int tid  = threadIdx.x;
    const int lane = tid & 63;
    const int wid  = tid >> 6;
    const int wr   = wid >> 1;
    const int wc   = wid & 1;
    const long mbase = (long)bb * SS + tile * 128;
    const int  nbase = nt * 128;

    f32x4 acc[4][4];
    #pragma unroll
    for (int m = 0; m < 4; ++m)
        #pragma unroll
        for (int n = 0; n < 4; ++n)
            acc[m][n] = (f32x4){0.f, 0.f, 0.f, 0.f};

    const short* ag0 = encb + (mbase + (tid >> 2)) * (long)HE + (tid & 3) * 8;
    const short* ag1 = ag0 + 64 * (long)HE;
    const short* bg0 = wkb + ((long)(nbase + (tid >> 2))) * HE + (tid & 3) * 8;
    const short* bg1 = bg0 + 64 * (long)HE;

    const int frow = lane & 15;
    const int kby  = (lane >> 4) * 16;

    #define COMPUTE(BUF)                                                         \
        do {                                                                     \
            bf16x8 af[4], bfr[4];                                                \
            _Pragma("unroll")                                                    \
            for (int m = 0; m < 4; ++m)                                          \
                af[m] = *(const bf16x8*)((const char*)As[BUF]                    \
                          + (wr * 64 + m * 16 + frow) * 64 + kby);               \
            _Pragma("unroll")                                                    \
            for (int n = 0; n < 4; ++n)                                          \
                bfr[n] = *(const bf16x8*)((const char*)Bs[BUF]                   \
                          + (wc * 64 + n * 16 + frow) * 64 + kby);               \
            _Pragma("unroll")                                                    \
            for (int m = 0; m < 4; ++m)                                          \
                _Pragma("unroll")                                                \
                for (int n = 0; n < 4; ++n)                                      \
                    acc[m][n] = __builtin_amdgcn_mfma_f32_16x16x32_bf16(         \
                        af[m], bfr[n], acc[m][n], 0, 0, 0);                      \
        } while (0)

    for (int kt = 0; kt < NT; kt += 2) {
        const int ko0 = kt * 32;
        const int ko1 = ko0 + 32;
        gload16(ag0 + ko0, (char*)As[0] + wid * 1024);
        gload16(ag1 + ko0, (char*)As[0] + 4096 + wid * 1024);
        gload16(bg0 + ko0, (char*)Bs[0] + wid * 1024);
        gload16(bg1 + ko0, (char*)Bs[0] + 4096 + wid * 1024);
        gload16(ag0 + ko1, (char*)As[1] + wid * 1024);
        gload16(ag1 + ko1, (char*)As[1] + 4096 + wid * 1024);
        gload16(bg0 + ko1, (char*)Bs[1] + wid * 1024);
        gload16(bg1 + ko1, (char*)Bs[1] + 4096 + wid * 1024);
        __syncthreads();
        COMPUTE(0);
        COMPUTE(1);
        __syncthreads();
    }
    #undef COMPUTE

    float qq[4], vv[4];
    #pragma unroll
    for (int n = 0; n < 4; ++n) {
        const int c = nbase + wc * 64 + n * 16 + frow;
        qq[n] = qv[bb * HD + c];
        vv[n] = ven[c];
    }
    float p[4][4];
    #pragma unroll
    for (int m = 0; m < 4; ++m) {
        #pragma unroll
        for (int rg = 0; rg < 4; ++rg) {
            float s = 0.f;
            #pragma unroll
            for (int n = 0; n < 4; ++n) {
                const float x = acc[m][n][rg] + qq[n];
                const float e = __expf(2.f * x);
                const float t = 1.f - 2.f * __builtin_amdgcn_rcpf(e + 1.f);
                s += vv[n] * t;
            }
            #pragma unroll
            for (int msk = 1; msk <= 8; msk <<= 1)
                s += __shfl_xor(s, msk, 64);
            p[m][rg] = s;
        }
    }
    if ((lane & 15) == 0) {
        const int g = lane >> 4;
        float* dst = sp + (long)(nt * 2 + wc) * MM;
        #pragma unroll
        for (int m = 0; m < 4; ++m)
            #pragma unroll
            for (int rg = 0; rg < 4; ++rg)
                dst[mbase + wr * 64 + m * 16 + g * 4 + rg] = p[m][rg];
    }
}

// ---------------- softmax over compacted domain; zero + scatter to attn ----------------
__global__ __launch_bounds__(256) void softmax_kernel(const float* __restrict__ sp,
                                                      const int* __restrict__ idx,
                                                      const int* __restrict__ cnt,
                                                      float* __restrict__ attn,
                                                      float* __restrict__ wcomp) {
    const int b = blockIdx.x;
    const int tid = threadIdx.x;
    const int lane = tid & 63;
    const int wid = tid >> 6;
    const int n = cnt[b];
    #pragma unroll
    for (int i = 0; i < 8; ++i)
        attn[b * SS + tid + i * 256] = 0.f;
    __shared__ float red[4];
    float sc[8];
    float mx = -3.0e38f;
    #pragma unroll
    for (int i = 0; i < 8; ++i) {
        const int j = tid + i * 256;
        float v = -3.0e38f;
        if (j < n) {
            v = 0.f;
            #pragma unroll
            for (int k = 0; k < 16; ++k)
                v += sp[(long)k * MM + b * SS + j];
        }
        sc[i] = v;
        mx = fmaxf(mx, v);
    }
    #pragma unroll
    for (int off = 32; off > 0; off >>= 1)
        mx = fmaxf(mx, __shfl_xor(mx, off, 64));
    if (lane == 0) red[wid] = mx;
    __syncthreads();
    mx = fmaxf(fmaxf(red[0], red[1]), fmaxf(red[2], red[3]));
    __syncthreads();
    float sum = 0.f;
    #pragma unroll
    for (int i = 0; i < 8; ++i) {
        const float e = (sc[i] > -1.0e38f) ? __expf(sc[i] - mx) : 0.f;
        sc[i] = e;
        sum += e;
    }
    #pragma unroll
    for (int off = 32; off > 0; off >>= 1)
        sum += __shfl_xor(sum, off, 64);
    if (lane == 0) red[wid] = sum;
    __syncthreads();
    sum = red[0] + red[1] + red[2] + red[3];
    const float inv = 1.f / sum;
    #pragma unroll
    for (int i = 0; i < 8; ++i) {
        const int j = tid + i * 256;
        const float w = sc[i] * inv;
        wcomp[b * SS + j] = w;
        if (j < n) attn[b * SS + idx[b * SS + j]] = w;
    }
}

// ---------------- context over compacted bf16 rows ----------------
__global__ __launch_bounds__(256) void ctx_partial_kernel(const short* __restrict__ encb,
                                                          const float* __restrict__ wcomp,
                                                          const int* __restrict__ cnt,
                                                          float* __restrict__ cp) {
    const int b = blockIdx.x >> 5;
    const int chunk = blockIdx.x & 31;
    const int tid = threadIdx.x;
    float* dst = cp + ((long)(b * 32 + chunk)) * HE + tid * 4;
    if (chunk * 64 >= cnt[b]) {
        *(f32x4*)dst = (f32x4){0.f, 0.f, 0.f, 0.f};
        return;
    }
    const short* ep = encb + ((long)b * SS + chunk * 64) * HE + tid * 4;
    const float* ap = wcomp + b * SS + chunk * 64;
    f32x4 acc = (f32x4){0.f, 0.f, 0.f, 0.f};
    #pragma unroll 4
    for (int s = 0; s < 64; ++s) {
        const float w = ap[s];
        const short4v v = *(const short4v*)(ep + (long)s * HE);
        acc[0] += w * bf2f(v[0]);
        acc[1] += w * bf2f(v[1]);
        acc[2] += w * bf2f(v[2]);
        acc[3] += w * bf2f(v[3]);
    }
    *(f32x4*)dst = acc;
}

__global__ __launch_bounds__(256) void ctx_reduce_kernel(const float* __restrict__ cp,
                                                         float* __restrict__ out) {
    const int o = blockIdx.x * 256 + threadIdx.x;
    const int b = o >> 10;
    const int e = o & 1023;
    float s = 0.f;
    #pragma unroll
    for (int c = 0; c < 32; ++c)
        s += cp[((long)(b * 32 + c)) * HE + e];
    out[o] = s;
}

extern "C" void kernel_launch(void* const* d_in, const int* in_sizes, int n_in,
                              void* d_out, int out_size, void* d_ws, size_t ws_size,
                              hipStream_t stream) {
    const float* dh   = (const float*)d_in[0];
    const float* enc  = (const float*)d_in[1];
    const int*   mask = (const int*)d_in[2];
    const float* Wq   = (const float*)d_in[3];
    const float* Wk   = (const float*)d_in[4];
    const float* Ve   = (const float*)d_in[5];

    float* out  = (float*)d_out;
    float* ctx  = out;
    float* attn = out + NB * HD;

    float* ws    = (float*)d_ws;
    float* wq_   = ws;                            // 32768 f
    float* sp    = ws + 32768;                    // 16 * 65536 f (4 MB)
    float* cp    = sp + 16 * (long)MM;            // 32*32*1024 f (4 MB)
    short* wkb   = (short*)(cp + 32 * 32 * HE);   // 1M bf16 (2 MB)
    float* wcomp = (float*)(wkb + (long)HD * HE); // 65536 f
    int*   idx   = (int*)(wcomp + MM);            // 65536 i
    int*   cnt   = idx + MM;                      // 32 i (+pad)
    short* encb  = (short*)(cnt + 64);            // 67.1M bf16 (128 MB)

    prep_kernel<<<776, 256, 0, stream>>>(mask, dh, Wq, Wk, idx, cnt, wq_, wkb);
    cvt_enc_kernel<<<NB * 128, 256, 0, stream>>>(enc, idx, cnt, encb);
    score_mfma_kernel<<<4096, 256, 0, stream>>>(encb, wkb, wq_, Ve, cnt, sp);
    softmax_kernel<<<NB, 256, 0, stream>>>(sp, idx, cnt, attn, wcomp);
    ctx_partial_kernel<<<1024, 256, 0, stream>>>(encb, wcomp, cnt, cp);
    ctx_reduce_kernel<<<128, 256, 0, stream>>>(cp, ctx);
}